// Round 8
// baseline (40.913 us; speedup 1.0000x reference)
//
#include <hip/hip_runtime.h>
#include <hip/hip_bf16.h>

typedef __attribute__((ext_vector_type(8))) short s8v;     // 8 bf16 = 16B
typedef __attribute__((ext_vector_type(4))) float f4v;     // fp32 accum

__device__ __forceinline__ ushort f2bf(float f) {
    __hip_bfloat16 h = __float2bfloat16(f);
    return __builtin_bit_cast(ushort, h);
}

// LDS k-slot swizzle on row bits 1-4 (handles stride-1 and stride-8 row patterns)
__device__ __forceinline__ int fsw(int row) { return ((row >> 1) ^ (row >> 3)) & 3; }

__device__ __forceinline__ void gload16(const ushort* g, ushort* l) {
    __builtin_amdgcn_global_load_lds(
        (const __attribute__((address_space(1))) unsigned*)g,
        (__attribute__((address_space(3))) unsigned*)l, 16, 0, 0);
}

__device__ __forceinline__ void cvtw16(ushort* p, float4 a, float4 b) {
    s8v u;
    u[0] = (short)f2bf(a.x); u[1] = (short)f2bf(a.y);
    u[2] = (short)f2bf(a.z); u[3] = (short)f2bf(a.w);
    u[4] = (short)f2bf(b.x); u[5] = (short)f2bf(b.y);
    u[6] = (short)f2bf(b.z); u[7] = (short)f2bf(b.w);
    *(s8v*)p = u;
}

// scatter-write 8 bf16 down a column (transposed staging), swizzled
__device__ __forceinline__ void scatw(ushort* L, int c8, int d, float4 a, float4 b) {
    float v[8] = { a.x, a.y, a.z, a.w, b.x, b.y, b.z, b.w };
#pragma unroll
    for (int i = 0; i < 8; ++i) {
        int row = c8 + i;
        L[row * 32 + (((d >> 3) ^ fsw(row)) << 3) + (d & 7)] = f2bf(v[i]);
    }
}

// ===== 64x64 S-GEMM from fp32 (D = X @ Y^T, ld 1024), 8 waves split-K =====
template<int NT>   // NT = (K/2)/32
__device__ __forceinline__ void gemmS(
    const float* __restrict__ Xb, const float* __restrict__ Yb,
    ushort* lds, int row0, int col0, ushort* __restrict__ O, int ldo) {
    const int tid = threadIdx.x, wave = tid >> 6, lane = tid & 63;
    const int g = wave >> 2, w4 = wave & 3;
    const int wr = w4 >> 1, wc = w4 & 1;
    const int rA = lane & 15, kg = lane >> 4;
    const int tg = tid & 255;
    const int srow = tg >> 2, slot = tg & 3;
    const int kb = g * (NT * 32);
    ushort* LA = lds + g * 16384;
    ushort* LB = LA + 8192;
    const int wadr = srow * 32 + ((slot ^ fsw(srow)) << 3);
    const float* gx = Xb + (size_t)(row0 + srow) * 1024 + kb + slot * 8;
    const float* gy = Yb + (size_t)(col0 + srow) * 1024 + kb + slot * 8;
    f4v acc[2][2] = {};
    __syncthreads();

    float4 bx[4][2], by[4][2];
#pragma unroll
    for (int p = 0; p < 3; ++p) {
        bx[p][0] = *(const float4*)(gx + p * 32);
        bx[p][1] = *(const float4*)(gx + p * 32 + 4);
        by[p][0] = *(const float4*)(gy + p * 32);
        by[p][1] = *(const float4*)(gy + p * 32 + 4);
    }
    cvtw16(LA + wadr, bx[0][0], bx[0][1]);
    cvtw16(LB + wadr, by[0][0], by[0][1]);

#pragma unroll
    for (int t = 0; t < NT; ++t) {
        if (t + 3 < NT) {
            const int bi = (t + 3) & 3;
            bx[bi][0] = *(const float4*)(gx + (t + 3) * 32);
            bx[bi][1] = *(const float4*)(gx + (t + 3) * 32 + 4);
            by[bi][0] = *(const float4*)(gy + (t + 3) * 32);
            by[bi][1] = *(const float4*)(gy + (t + 3) * 32 + 4);
        }
        if (t + 1 < NT) {
            const int bi = (t + 1) & 3;
            cvtw16(LA + ((t + 1) & 3) * 2048 + wadr, bx[bi][0], bx[bi][1]);
            cvtw16(LB + ((t + 1) & 3) * 2048 + wadr, by[bi][0], by[bi][1]);
        }
        asm volatile("s_waitcnt lgkmcnt(0)" ::: "memory");
        __builtin_amdgcn_s_barrier();
        __builtin_amdgcn_sched_barrier(0);
        const ushort* pa = LA + (t & 3) * 2048;
        const ushort* pb = LB + (t & 3) * 2048;
        s8v a[2], b[2];
#pragma unroll
        for (int m = 0; m < 2; ++m) {
            int row = wr * 32 + m * 16 + rA;
            a[m] = *(const s8v*)&pa[row * 32 + ((kg ^ fsw(row)) << 3)];
        }
#pragma unroll
        for (int n = 0; n < 2; ++n) {
            int row = wc * 32 + n * 16 + rA;
            b[n] = *(const s8v*)&pb[row * 32 + ((kg ^ fsw(row)) << 3)];
        }
        __builtin_amdgcn_s_setprio(1);
#pragma unroll
        for (int m = 0; m < 2; ++m)
#pragma unroll
            for (int n = 0; n < 2; ++n)
                acc[m][n] = __builtin_amdgcn_mfma_f32_16x16x32_bf16(a[m], b[n], acc[m][n], 0, 0, 0);
        __builtin_amdgcn_s_setprio(0);
    }
    __syncthreads();
    float* red = (float*)lds;
    if (g == 1) {
#pragma unroll
        for (int m = 0; m < 2; ++m)
#pragma unroll
            for (int n = 0; n < 2; ++n)
                *(f4v*)&red[(w4 * 64 + lane) * 16 + (m * 2 + n) * 4] = acc[m][n];
    }
    __syncthreads();
    if (g == 0) {
        int r4 = (lane >> 4) * 4, cl = lane & 15;
#pragma unroll
        for (int m = 0; m < 2; ++m)
#pragma unroll
            for (int n = 0; n < 2; ++n) {
                f4v o = *(const f4v*)&red[(w4 * 64 + lane) * 16 + (m * 2 + n) * 4];
                f4v s = acc[m][n] + o;
                int row = row0 + wr * 32 + m * 16 + r4;
                int col = col0 + wc * 32 + n * 16 + cl;
#pragma unroll
                for (int r = 0; r < 4; ++r)
                    O[(size_t)(row + r) * ldo + col] = f2bf(s[r]);
            }
    }
}

// ===== 64x64 weight-GEMM from fp32 (K=256, split-K). XT=1: X transposed =====
template<int XT>
__device__ __forceinline__ void gemmWT(
    const float* __restrict__ Xw, const float* __restrict__ Yw,
    ushort* lds, int row0, int col0, ushort* __restrict__ O, int ldo) {
    const int NT = 4;
    const int tid = threadIdx.x, wave = tid >> 6, lane = tid & 63;
    const int g = wave >> 2, w4 = wave & 3;
    const int wr = w4 >> 1, wc = w4 & 1;
    const int rA = lane & 15, kg = lane >> 4;
    const int tg = tid & 255;
    const int kb = g * 128;
    ushort* LA = lds + g * 16384;
    ushort* LB = LA + 8192;
    const int dT = tg >> 3, c8 = (tg & 7) * 8;
    const int srow = tg >> 2, slot = tg & 3;
    const int wadr = srow * 32 + ((slot ^ fsw(srow)) << 3);
    f4v acc[2][2] = {};
    __syncthreads();

    float4 bx[4][2], by[4][2];
#pragma unroll
    for (int p = 0; p < 3; ++p) {
        if (XT) {
            bx[p][0] = *(const float4*)(Xw + (size_t)(kb + p * 32 + dT) * 256 + row0 + c8);
            bx[p][1] = *(const float4*)(Xw + (size_t)(kb + p * 32 + dT) * 256 + row0 + c8 + 4);
        } else {
            bx[p][0] = *(const float4*)(Xw + (size_t)(row0 + srow) * 1024 + kb + p * 32 + slot * 8);
            bx[p][1] = *(const float4*)(Xw + (size_t)(row0 + srow) * 1024 + kb + p * 32 + slot * 8 + 4);
        }
        by[p][0] = *(const float4*)(Yw + (size_t)(kb + p * 32 + dT) * 256 + col0 + c8);
        by[p][1] = *(const float4*)(Yw + (size_t)(kb + p * 32 + dT) * 256 + col0 + c8 + 4);
    }
    if (XT) scatw(LA, c8, dT, bx[0][0], bx[0][1]);
    else    cvtw16(LA + wadr, bx[0][0], bx[0][1]);
    scatw(LB, c8, dT, by[0][0], by[0][1]);

#pragma unroll
    for (int t = 0; t < NT; ++t) {
        if (t + 3 < NT) {
            const int bi = (t + 3) & 3;
            if (XT) {
                bx[bi][0] = *(const float4*)(Xw + (size_t)(kb + (t + 3) * 32 + dT) * 256 + row0 + c8);
                bx[bi][1] = *(const float4*)(Xw + (size_t)(kb + (t + 3) * 32 + dT) * 256 + row0 + c8 + 4);
            } else {
                bx[bi][0] = *(const float4*)(Xw + (size_t)(row0 + srow) * 1024 + kb + (t + 3) * 32 + slot * 8);
                bx[bi][1] = *(const float4*)(Xw + (size_t)(row0 + srow) * 1024 + kb + (t + 3) * 32 + slot * 8 + 4);
            }
            by[bi][0] = *(const float4*)(Yw + (size_t)(kb + (t + 3) * 32 + dT) * 256 + col0 + c8);
            by[bi][1] = *(const float4*)(Yw + (size_t)(kb + (t + 3) * 32 + dT) * 256 + col0 + c8 + 4);
        }
        if (t + 1 < NT) {
            const int bi = (t + 1) & 3;
            ushort* la = LA + ((t + 1) & 3) * 2048;
            ushort* lb = LB + ((t + 1) & 3) * 2048;
            if (XT) scatw(la, c8, dT, bx[bi][0], bx[bi][1]);
            else    cvtw16(la + wadr, bx[bi][0], bx[bi][1]);
            scatw(lb, c8, dT, by[bi][0], by[bi][1]);
        }
        asm volatile("s_waitcnt lgkmcnt(0)" ::: "memory");
        __builtin_amdgcn_s_barrier();
        __builtin_amdgcn_sched_barrier(0);
        const ushort* pa = LA + (t & 3) * 2048;
        const ushort* pb = LB + (t & 3) * 2048;
        s8v a[2], b[2];
#pragma unroll
        for (int m = 0; m < 2; ++m) {
            int row = wr * 32 + m * 16 + rA;
            a[m] = *(const s8v*)&pa[row * 32 + ((kg ^ fsw(row)) << 3)];
        }
#pragma unroll
        for (int n = 0; n < 2; ++n) {
            int row = wc * 32 + n * 16 + rA;
            b[n] = *(const s8v*)&pb[row * 32 + ((kg ^ fsw(row)) << 3)];
        }
        __builtin_amdgcn_s_setprio(1);
#pragma unroll
        for (int m = 0; m < 2; ++m)
#pragma unroll
            for (int n = 0; n < 2; ++n)
                acc[m][n] = __builtin_amdgcn_mfma_f32_16x16x32_bf16(a[m], b[n], acc[m][n], 0, 0, 0);
        __builtin_amdgcn_s_setprio(0);
    }
    __syncthreads();
    float* red = (float*)lds;
    if (g == 1) {
#pragma unroll
        for (int m = 0; m < 2; ++m)
#pragma unroll
            for (int n = 0; n < 2; ++n)
                *(f4v*)&red[(w4 * 64 + lane) * 16 + (m * 2 + n) * 4] = acc[m][n];
    }
    __syncthreads();
    if (g == 0) {
        int r4 = (lane >> 4) * 4, cl = lane & 15;
#pragma unroll
        for (int m = 0; m < 2; ++m)
#pragma unroll
            for (int n = 0; n < 2; ++n) {
                f4v o = *(const f4v*)&red[(w4 * 64 + lane) * 16 + (m * 2 + n) * 4];
                f4v s = acc[m][n] + o;
                int row = row0 + wr * 32 + m * 16 + r4;
                int col = col0 + wc * 32 + n * 16 + cl;
#pragma unroll
                for (int r = 0; r < 4; ++r)
                    O[(size_t)(row + r) * ldo + col] = f2bf(s[r]);
            }
    }
}

// ===== 64x64 bf16 GEMM (gload_lds), 8-wave split-K — GT stage (K=1024) =====
__device__ __forceinline__ void gemm64x8(
    const ushort* __restrict__ Xb, const ushort* __restrict__ Yb,
    int ldx, int ldy, ushort* lds, int row0, int col0, int K,
    ushort* __restrict__ O, int ldo) {
    const int tid = threadIdx.x, wave = tid >> 6, lane = tid & 63;
    const int g = wave >> 2, w4 = wave & 3;
    const int wr = w4 >> 1, wc = w4 & 1;
    const int rA = lane & 15, kg = lane >> 4;
    const int srow = w4 * 16 + (lane >> 2);
    const int scol = ((lane & 3) ^ fsw(srow)) * 8;
    const int K2 = K >> 1, NT = K2 >> 5, kb = g * K2;
    ushort* LA = lds + g * 16384;
    ushort* LB = LA + 8192;
    f4v acc[2][2] = {};
    __syncthreads();
    const ushort* gx = Xb + (size_t)(row0 + srow) * ldx + kb + scol;
    const ushort* gy = Yb + (size_t)(col0 + srow) * ldy + kb + scol;
    gload16(gx,      LA + w4 * 512);
    gload16(gy,      LB + w4 * 512);
    gload16(gx + 32, LA + 2048 + w4 * 512);
    gload16(gy + 32, LB + 2048 + w4 * 512);
    for (int t = 0; t < NT; ++t) {
        if (t + 2 < NT) {
            int s2 = (t + 2) & 3, kt = (t + 2) << 5;
            gload16(gx + kt, LA + s2 * 2048 + w4 * 512);
            gload16(gy + kt, LB + s2 * 2048 + w4 * 512);
            asm volatile("s_waitcnt vmcnt(4)" ::: "memory");
        } else if (t + 1 < NT) {
            asm volatile("s_waitcnt vmcnt(2)" ::: "memory");
        } else {
            asm volatile("s_waitcnt vmcnt(0)" ::: "memory");
        }
        __builtin_amdgcn_s_barrier();
        __builtin_amdgcn_sched_barrier(0);
        const ushort* pa = LA + (t & 3) * 2048;
        const ushort* pb = LB + (t & 3) * 2048;
        s8v a[2], b[2];
#pragma unroll
        for (int m = 0; m < 2; ++m) {
            int row = wr * 32 + m * 16 + rA;
            a[m] = *(const s8v*)&pa[row * 32 + ((kg ^ fsw(row)) << 3)];
        }
#pragma unroll
        for (int n = 0; n < 2; ++n) {
            int row = wc * 32 + n * 16 + rA;
            b[n] = *(const s8v*)&pb[row * 32 + ((kg ^ fsw(row)) << 3)];
        }
        __builtin_amdgcn_s_setprio(1);
#pragma unroll
        for (int m = 0; m < 2; ++m)
#pragma unroll
            for (int n = 0; n < 2; ++n)
                acc[m][n] = __builtin_amdgcn_mfma_f32_16x16x32_bf16(a[m], b[n], acc[m][n], 0, 0, 0);
        __builtin_amdgcn_s_setprio(0);
    }
    __syncthreads();
    float* red = (float*)lds;
    if (g == 1) {
#pragma unroll
        for (int m = 0; m < 2; ++m)
#pragma unroll
            for (int n = 0; n < 2; ++n)
                *(f4v*)&red[(w4 * 64 + lane) * 16 + (m * 2 + n) * 4] = acc[m][n];
    }
    __syncthreads();
    if (g == 0) {
        int r4 = (lane >> 4) * 4, cl = lane & 15;
#pragma unroll
        for (int m = 0; m < 2; ++m)
#pragma unroll
            for (int n = 0; n < 2; ++n) {
                f4v o = *(const f4v*)&red[(w4 * 64 + lane) * 16 + (m * 2 + n) * 4];
                f4v s = acc[m][n] + o;
                int row = row0 + wr * 32 + m * 16 + r4;
                int col = col0 + wc * 32 + n * 16 + cl;
#pragma unroll
                for (int r = 0; r < 4; ++r)
                    O[(size_t)(row + r) * ldo + col] = f2bf(s[r]);
            }
    }
}

// ===== 128x128 bf16 GEMM (gload_lds), 8 waves (2x4), acc 4x2 — T1 stage =====
__device__ __forceinline__ void gemm128x8(
    const ushort* __restrict__ Xb, const ushort* __restrict__ Yb,
    int ldx, int ldy, ushort* lds, int row0, int col0, int K,
    ushort* __restrict__ O, int ldo) {
    const int tid = threadIdx.x, wave = tid >> 6, lane = tid & 63;
    const int wr = wave >> 2, wc = wave & 3;
    const int rA = lane & 15, kg = lane >> 4;
    const int srow = wave * 16 + (lane >> 2);
    const int scol = ((lane & 3) ^ fsw(srow)) * 8;
    const int NT = K >> 5;
    ushort* LA = lds;
    ushort* LB = lds + 16384;
    f4v acc[4][2] = {};
    __syncthreads();
    const ushort* gx = Xb + (size_t)(row0 + srow) * ldx + scol;
    const ushort* gy = Yb + (size_t)(col0 + srow) * ldy + scol;
#pragma unroll
    for (int p = 0; p < 2; ++p) {
        gload16(gx + p * 32, LA + p * 4096 + wave * 512);
        gload16(gy + p * 32, LB + p * 4096 + wave * 512);
    }
    for (int t = 0; t < NT; ++t) {
        if (t + 2 < NT) {
            int s2 = (t + 2) & 3, kt = (t + 2) << 5;
            gload16(gx + kt, LA + s2 * 4096 + wave * 512);
            gload16(gy + kt, LB + s2 * 4096 + wave * 512);
            asm volatile("s_waitcnt vmcnt(4)" ::: "memory");
        } else if (t + 1 < NT) {
            asm volatile("s_waitcnt vmcnt(2)" ::: "memory");
        } else {
            asm volatile("s_waitcnt vmcnt(0)" ::: "memory");
        }
        __builtin_amdgcn_s_barrier();
        __builtin_amdgcn_sched_barrier(0);
        const ushort* pa = LA + (t & 3) * 4096;
        const ushort* pb = LB + (t & 3) * 4096;
        s8v a[4], b[2];
#pragma unroll
        for (int m = 0; m < 4; ++m) {
            int row = wr * 64 + m * 16 + rA;
            a[m] = *(const s8v*)&pa[row * 32 + ((kg ^ fsw(row)) << 3)];
        }
#pragma unroll
        for (int n = 0; n < 2; ++n) {
            int row = wc * 32 + n * 16 + rA;
            b[n] = *(const s8v*)&pb[row * 32 + ((kg ^ fsw(row)) << 3)];
        }
        __builtin_amdgcn_s_setprio(1);
#pragma unroll
        for (int m = 0; m < 4; ++m)
#pragma unroll
            for (int n = 0; n < 2; ++n)
                acc[m][n] = __builtin_amdgcn_mfma_f32_16x16x32_bf16(a[m], b[n], acc[m][n], 0, 0, 0);
        __builtin_amdgcn_s_setprio(0);
    }
    int r4 = (lane >> 4) * 4, cl = lane & 15;
#pragma unroll
    for (int m = 0; m < 4; ++m)
#pragma unroll
        for (int n = 0; n < 2; ++n) {
            int row = row0 + wr * 64 + m * 16 + r4;
            int col = col0 + wc * 32 + n * 16 + cl;
#pragma unroll
            for (int r = 0; r < 4; ++r)
                O[(size_t)(row + r) * ldo + col] = f2bf(acc[m][n][r]);
        }
}

// ===== OUT: 128x128, A = GT (bf16, gload_lds), B = x native fp32 (ld 1024),
//            transposed reg->LDS staging; fp32 out + bias. K=256.
__device__ __forceinline__ void gemmOUT(
    const ushort* __restrict__ Ga, const float* __restrict__ Xf,
    ushort* lds, int row0, int col0,
    float* __restrict__ O, const float* __restrict__ bias) {
    const int tid = threadIdx.x, wave = tid >> 6, lane = tid & 63;
    const int wr = wave >> 2, wc = wave & 3;
    const int rA = lane & 15, kg = lane >> 4;
    const int srowA = wave * 16 + (lane >> 2);
    const int scolA = ((lane & 3) ^ fsw(srowA)) * 8;
    ushort* LA = lds;              // 4 slots x 4096 ushorts
    ushort* LB = lds + 16384;
    const int kk = tid >> 4, l8 = (tid & 15) * 8;
    int wadr[8];
#pragma unroll
    for (int i = 0; i < 8; ++i) {
        int row = l8 + i;
        wadr[i] = row * 32 + (((kk >> 3) ^ fsw(row)) << 3) + (kk & 7);
    }
    const ushort* gA = Ga + (size_t)(row0 + srowA) * 256 + scolA;
    const float* gB = Xf + (size_t)kk * 1024 + col0 + l8;
    f4v acc[4][2] = {};
    __syncthreads();

    float4 ra[4], rb[4];           // rotating B-reg slots (pairs)
    gload16(gA + 0, LA + 0 * 4096 + wave * 512);
    ra[0] = *(const float4*)(gB);
    rb[0] = *(const float4*)(gB + 4);
    gload16(gA + 32, LA + 1 * 4096 + wave * 512);
    ra[1] = *(const float4*)(gB + 32768);
    rb[1] = *(const float4*)(gB + 32768 + 4);
    asm volatile("s_waitcnt vmcnt(0)" ::: "memory");
    {
        float v[8] = { ra[0].x, ra[0].y, ra[0].z, ra[0].w, rb[0].x, rb[0].y, rb[0].z, rb[0].w };
#pragma unroll
        for (int i = 0; i < 8; ++i) LB[wadr[i]] = f2bf(v[i]);
    }
    asm volatile("s_waitcnt lgkmcnt(0)" ::: "memory");
    __builtin_amdgcn_s_barrier();
    __builtin_amdgcn_sched_barrier(0);

#pragma unroll
    for (int t = 0; t < 8; ++t) {
        if (t + 1 < 8) {
            if (t + 2 < 8) {
                gload16(gA + (t + 2) * 32, LA + ((t + 2) & 3) * 4096 + wave * 512);
                ra[(t + 2) & 3] = *(const float4*)(gB + (size_t)(t + 2) * 32768);
                rb[(t + 2) & 3] = *(const float4*)(gB + (size_t)(t + 2) * 32768 + 4);
            }
            {
                const int bi = (t + 1) & 3;
                float v[8] = { ra[bi].x, ra[bi].y, ra[bi].z, ra[bi].w,
                               rb[bi].x, rb[bi].y, rb[bi].z, rb[bi].w };
                ushort* lb = LB + bi * 4096;
#pragma unroll
                for (int i = 0; i < 8; ++i) lb[wadr[i]] = f2bf(v[i]);
            }
            if (t + 2 < 8) { asm volatile("s_waitcnt vmcnt(3)" ::: "memory"); }
            else           { asm volatile("s_waitcnt vmcnt(0)" ::: "memory"); }
            asm volatile("s_waitcnt lgkmcnt(0)" ::: "memory");
            __builtin_amdgcn_s_barrier();
            __builtin_amdgcn_sched_barrier(0);
        }
        const ushort* pa = LA + (t & 3) * 4096;
        const ushort* pb = LB + (t & 3) * 4096;
        s8v a[4], b[2];
#pragma unroll
        for (int m = 0; m < 4; ++m) {
            int row = wr * 64 + m * 16 + rA;
            a[m] = *(const s8v*)&pa[row * 32 + ((kg ^ fsw(row)) << 3)];
        }
#pragma unroll
        for (int n = 0; n < 2; ++n) {
            int row = wc * 32 + n * 16 + rA;
            b[n] = *(const s8v*)&pb[row * 32 + ((kg ^ fsw(row)) << 3)];
        }
        __builtin_amdgcn_s_setprio(1);
#pragma unroll
        for (int m = 0; m < 4; ++m)
#pragma unroll
            for (int n = 0; n < 2; ++n)
                acc[m][n] = __builtin_amdgcn_mfma_f32_16x16x32_bf16(a[m], b[n], acc[m][n], 0, 0, 0);
        __builtin_amdgcn_s_setprio(0);
    }
    int r4 = (lane >> 4) * 4, cl = lane & 15;
#pragma unroll
    for (int m = 0; m < 4; ++m)
#pragma unroll
        for (int n = 0; n < 2; ++n) {
            int row = row0 + wr * 64 + m * 16 + r4;
            int col = col0 + wc * 32 + n * 16 + cl;
#pragma unroll
            for (int r = 0; r < 4; ++r)
                O[(size_t)(row + r) * 1024 + col] = acc[m][n][r] + bias[row + r];
        }
}

// ===== kernel 1: S (256 blocks, XCD-mapped) + A (blocks 0..63) + BT (64..127)
__global__ __launch_bounds__(512, 2) void kSP(
    const float* __restrict__ x, const float* __restrict__ Wq,
    const float* __restrict__ Wk, const float* __restrict__ Wv,
    const float* __restrict__ Wo,
    ushort* __restrict__ S16, ushort* __restrict__ A16, ushort* __restrict__ BT) {
    __shared__ __align__(16) ushort lds[32768];
    const int bid = blockIdx.x;
    int xcd = bid & 7, idx = bid >> 3;
    int b = 2 * xcd + (idx >> 4), t = idx & 15;
    const float* xb = x + (size_t)b * 262144;
    gemmS<16>(xb, xb, lds, (t >> 2) * 64, (t & 3) * 64, S16 + (size_t)b * 65536, 256);
    if (bid < 64) {
        int h = bid >> 4, t2 = bid & 15;
        gemmWT<1>(Wq + (size_t)h * 65536, Wk + (size_t)h * 65536, lds,
                  (t2 >> 2) * 64, (t2 & 3) * 64, A16 + (size_t)h * 65536, 256);
    } else if (bid < 128) {
        int q = bid - 64, h = q >> 4, t2 = q & 15;
        gemmWT<0>(Wo + (size_t)h * 256, Wv + (size_t)h * 65536, lds,
                  (t2 >> 2) * 64, (t2 & 3) * 64, BT + (size_t)h * 256, 1024);
    }
}

// ===== kernel 2: T1_b[:, h*256:] = A_h @ S_b^T
__global__ __launch_bounds__(512, 2) void kT1(
    const ushort* __restrict__ A16, const ushort* __restrict__ S16,
    ushort* __restrict__ T1) {
    __shared__ __align__(16) ushort lds[32768];
    int j = blockIdx.x, xcd = j & 7, idx = j >> 3;
    int b = 2 * xcd + (idx >> 4), h = (idx >> 2) & 3, tile = idx & 3;
    gemm128x8(A16 + (size_t)h * 65536, S16 + (size_t)b * 65536, 256, 256, lds,
              (tile >> 1) * 128, (tile & 1) * 128, 256,
              T1 + (size_t)b * 262144 + h * 256, 1024);
}

// ===== kernel 3: GT_b = BT @ T1_b^T (K=1024)
__global__ __launch_bounds__(512, 2) void kGT(
    const ushort* __restrict__ BT, const ushort* __restrict__ T1,
    ushort* __restrict__ GT) {
    __shared__ __align__(16) ushort lds[32768];
    int j = blockIdx.x, xcd = j & 7, idx = j >> 3;
    int b = 2 * xcd + (idx >> 4), tile = idx & 15;
    gemm64x8(BT, T1 + (size_t)b * 262144, 1024, 1024, lds,
             (tile >> 2) * 64, (tile & 3) * 64, 1024, GT + (size_t)b * 65536, 256);
}

// ===== kernel 4: out_b = GT_b @ x_b + bias (fp32, reads x natively)
__global__ __launch_bounds__(512, 2) void kOUT(
    const ushort* __restrict__ GT, const float* __restrict__ x,
    float* __restrict__ out, const float* __restrict__ bias) {
    __shared__ __align__(16) ushort lds[32768];
    int j = blockIdx.x, xcd = j & 7, idx = j >> 3;
    int b = 2 * xcd + (idx >> 4), tile = idx & 15;
    gemmOUT(GT + (size_t)b * 65536, x + (size_t)b * 262144, lds,
            (tile >> 3) * 128, (tile & 7) * 128, out + (size_t)b * 262144, bias);
}

extern "C" void kernel_launch(void* const* d_in, const int* in_sizes, int n_in,
                              void* d_out, int out_size, void* d_ws, size_t ws_size,
                              hipStream_t stream) {
    const float* x  = (const float*)d_in[0];
    const float* Wq = (const float*)d_in[1];
    const float* Wk = (const float*)d_in[2];
    const float* Wv = (const float*)d_in[3];
    const float* Wo = (const float*)d_in[4];
    const float* Wb = (const float*)d_in[5];

    char* ws = (char*)d_ws;
    ushort* T1  = (ushort*)(ws + 0);           // [16][256][1024] bf16, 8 MB
    ushort* S16 = (ushort*)(ws + 16777216);    // [16][256][256]  bf16, 2 MB
    ushort* GT  = (ushort*)(ws + 20971520);    // [16][256][256]  bf16, 2 MB
    ushort* A16 = (ushort*)(ws + 25165824);    // [4][256][256]   bf16, 512 KB
    ushort* BT  = (ushort*)(ws + 26214400);    // [256][1024]     bf16, 512 KB

    hipLaunchKernelGGL(kSP,  dim3(256), dim3(512), 0, stream,
                       x, Wq, Wk, Wv, Wo, S16, A16, BT);
    hipLaunchKernelGGL(kT1,  dim3(256), dim3(512), 0, stream, A16, S16, T1);
    hipLaunchKernelGGL(kGT,  dim3(256), dim3(512), 0, stream, BT, T1, GT);
    hipLaunchKernelGGL(kOUT, dim3(256), dim3(512), 0, stream, GT, x, (float*)d_out, Wb);
}

// Round 10
// 39.718 us; speedup vs baseline: 1.0301x; 1.0301x over previous
//
#include <hip/hip_runtime.h>
#include <hip/hip_bf16.h>

typedef __attribute__((ext_vector_type(8))) short s8v;     // 8 bf16 = 16B
typedef __attribute__((ext_vector_type(4))) float f4v;     // fp32 accum

__device__ __forceinline__ ushort f2bf(float f) {
    __hip_bfloat16 h = __float2bfloat16(f);
    return __builtin_bit_cast(ushort, h);
}

// LDS k-slot swizzle on row bits 1-4 (handles stride-1 and stride-8 row patterns)
__device__ __forceinline__ int fsw(int row) { return ((row >> 1) ^ (row >> 3)) & 3; }

__device__ __forceinline__ void gload16(const ushort* g, ushort* l) {
    __builtin_amdgcn_global_load_lds(
        (const __attribute__((address_space(1))) unsigned*)g,
        (__attribute__((address_space(3))) unsigned*)l, 16, 0, 0);
}

__device__ __forceinline__ void cvtw16(ushort* p, float4 a, float4 b) {
    s8v u;
    u[0] = (short)f2bf(a.x); u[1] = (short)f2bf(a.y);
    u[2] = (short)f2bf(a.z); u[3] = (short)f2bf(a.w);
    u[4] = (short)f2bf(b.x); u[5] = (short)f2bf(b.y);
    u[6] = (short)f2bf(b.z); u[7] = (short)f2bf(b.w);
    *(s8v*)p = u;
}

// scatter-write 8 bf16 down a column (transposed staging), swizzled
__device__ __forceinline__ void scatw(ushort* L, int c8, int d, float4 a, float4 b) {
    float v[8] = { a.x, a.y, a.z, a.w, b.x, b.y, b.z, b.w };
#pragma unroll
    for (int i = 0; i < 8; ++i) {
        int row = c8 + i;
        L[row * 32 + (((d >> 3) ^ fsw(row)) << 3) + (d & 7)] = f2bf(v[i]);
    }
}

// ===== 64x64 S-GEMM from fp32 (S = x @ x^T, ld 1024), 8 waves split-K.
//       mirror!=0: also write transposed tile (symmetric S, off-diagonal).
__device__ __forceinline__ void gemmS(
    const float* __restrict__ Xb, ushort* lds, int row0, int col0,
    ushort* __restrict__ S, int mirror) {
    const int NT = 16;
    const int tid = threadIdx.x, wave = tid >> 6, lane = tid & 63;
    const int g = wave >> 2, w4 = wave & 3;
    const int wr = w4 >> 1, wc = w4 & 1;
    const int rA = lane & 15, kg = lane >> 4;
    const int tg = tid & 255;
    const int srow = tg >> 2, slot = tg & 3;
    const int kb = g * (NT * 32);
    ushort* LA = lds + g * 16384;
    ushort* LB = LA + 8192;
    const int wadr = srow * 32 + ((slot ^ fsw(srow)) << 3);
    const float* gx = Xb + (size_t)(row0 + srow) * 1024 + kb + slot * 8;
    const float* gy = Xb + (size_t)(col0 + srow) * 1024 + kb + slot * 8;
    f4v acc[2][2] = {};
    __syncthreads();

    float4 bx[4][2], by[4][2];
#pragma unroll
    for (int p = 0; p < 3; ++p) {
        bx[p][0] = *(const float4*)(gx + p * 32);
        bx[p][1] = *(const float4*)(gx + p * 32 + 4);
        by[p][0] = *(const float4*)(gy + p * 32);
        by[p][1] = *(const float4*)(gy + p * 32 + 4);
    }
    cvtw16(LA + wadr, bx[0][0], bx[0][1]);
    cvtw16(LB + wadr, by[0][0], by[0][1]);

#pragma unroll
    for (int t = 0; t < NT; ++t) {
        if (t + 3 < NT) {
            const int bi = (t + 3) & 3;
            bx[bi][0] = *(const float4*)(gx + (t + 3) * 32);
            bx[bi][1] = *(const float4*)(gx + (t + 3) * 32 + 4);
            by[bi][0] = *(const float4*)(gy + (t + 3) * 32);
            by[bi][1] = *(const float4*)(gy + (t + 3) * 32 + 4);
        }
        if (t + 1 < NT) {
            const int bi = (t + 1) & 3;
            cvtw16(LA + ((t + 1) & 3) * 2048 + wadr, bx[bi][0], bx[bi][1]);
            cvtw16(LB + ((t + 1) & 3) * 2048 + wadr, by[bi][0], by[bi][1]);
        }
        asm volatile("s_waitcnt lgkmcnt(0)" ::: "memory");
        __builtin_amdgcn_s_barrier();
        __builtin_amdgcn_sched_barrier(0);
        const ushort* pa = LA + (t & 3) * 2048;
        const ushort* pb = LB + (t & 3) * 2048;
        s8v a[2], b[2];
#pragma unroll
        for (int m = 0; m < 2; ++m) {
            int row = wr * 32 + m * 16 + rA;
            a[m] = *(const s8v*)&pa[row * 32 + ((kg ^ fsw(row)) << 3)];
        }
#pragma unroll
        for (int n = 0; n < 2; ++n) {
            int row = wc * 32 + n * 16 + rA;
            b[n] = *(const s8v*)&pb[row * 32 + ((kg ^ fsw(row)) << 3)];
        }
#pragma unroll
        for (int m = 0; m < 2; ++m)
#pragma unroll
            for (int n = 0; n < 2; ++n)
                acc[m][n] = __builtin_amdgcn_mfma_f32_16x16x32_bf16(a[m], b[n], acc[m][n], 0, 0, 0);
    }
    __syncthreads();
    float* red = (float*)lds;
    if (g == 1) {
#pragma unroll
        for (int m = 0; m < 2; ++m)
#pragma unroll
            for (int n = 0; n < 2; ++n)
                *(f4v*)&red[(w4 * 64 + lane) * 16 + (m * 2 + n) * 4] = acc[m][n];
    }
    __syncthreads();
    if (g == 0) {
        int r4 = (lane >> 4) * 4, cl = lane & 15;
#pragma unroll
        for (int m = 0; m < 2; ++m)
#pragma unroll
            for (int n = 0; n < 2; ++n) {
                f4v o = *(const f4v*)&red[(w4 * 64 + lane) * 16 + (m * 2 + n) * 4];
                f4v s = acc[m][n] + o;
                int row = row0 + wr * 32 + m * 16 + r4;
                int col = col0 + wc * 32 + n * 16 + cl;
                ushort4 tv = { f2bf(s[0]), f2bf(s[1]), f2bf(s[2]), f2bf(s[3]) };
                S[(size_t)(row + 0) * 256 + col] = tv.x;
                S[(size_t)(row + 1) * 256 + col] = tv.y;
                S[(size_t)(row + 2) * 256 + col] = tv.z;
                S[(size_t)(row + 3) * 256 + col] = tv.w;
                if (mirror)
                    *(ushort4*)&S[(size_t)col * 256 + row] = tv;   // transposed tile
            }
    }
}

// ===== 64x64 weight-GEMM from fp32 (K=256, split-K). XT=1: X transposed =====
template<int XT>
__device__ __forceinline__ void gemmWT(
    const float* __restrict__ Xw, const float* __restrict__ Yw,
    ushort* lds, int row0, int col0, ushort* __restrict__ O, int ldo) {
    const int NT = 4;
    const int tid = threadIdx.x, wave = tid >> 6, lane = tid & 63;
    const int g = wave >> 2, w4 = wave & 3;
    const int wr = w4 >> 1, wc = w4 & 1;
    const int rA = lane & 15, kg = lane >> 4;
    const int tg = tid & 255;
    const int kb = g * 128;
    ushort* LA = lds + g * 16384;
    ushort* LB = LA + 8192;
    const int dT = tg >> 3, c8 = (tg & 7) * 8;
    const int srow = tg >> 2, slot = tg & 3;
    const int wadr = srow * 32 + ((slot ^ fsw(srow)) << 3);
    f4v acc[2][2] = {};
    __syncthreads();

    float4 bx[4][2], by[4][2];
#pragma unroll
    for (int p = 0; p < 3; ++p) {
        if (XT) {
            bx[p][0] = *(const float4*)(Xw + (size_t)(kb + p * 32 + dT) * 256 + row0 + c8);
            bx[p][1] = *(const float4*)(Xw + (size_t)(kb + p * 32 + dT) * 256 + row0 + c8 + 4);
        } else {
            bx[p][0] = *(const float4*)(Xw + (size_t)(row0 + srow) * 1024 + kb + p * 32 + slot * 8);
            bx[p][1] = *(const float4*)(Xw + (size_t)(row0 + srow) * 1024 + kb + p * 32 + slot * 8 + 4);
        }
        by[p][0] = *(const float4*)(Yw + (size_t)(kb + p * 32 + dT) * 256 + col0 + c8);
        by[p][1] = *(const float4*)(Yw + (size_t)(kb + p * 32 + dT) * 256 + col0 + c8 + 4);
    }
    if (XT) scatw(LA, c8, dT, bx[0][0], bx[0][1]);
    else    cvtw16(LA + wadr, bx[0][0], bx[0][1]);
    scatw(LB, c8, dT, by[0][0], by[0][1]);

#pragma unroll
    for (int t = 0; t < NT; ++t) {
        if (t + 3 < NT) {
            const int bi = (t + 3) & 3;
            if (XT) {
                bx[bi][0] = *(const float4*)(Xw + (size_t)(kb + (t + 3) * 32 + dT) * 256 + row0 + c8);
                bx[bi][1] = *(const float4*)(Xw + (size_t)(kb + (t + 3) * 32 + dT) * 256 + row0 + c8 + 4);
            } else {
                bx[bi][0] = *(const float4*)(Xw + (size_t)(row0 + srow) * 1024 + kb + (t + 3) * 32 + slot * 8);
                bx[bi][1] = *(const float4*)(Xw + (size_t)(row0 + srow) * 1024 + kb + (t + 3) * 32 + slot * 8 + 4);
            }
            by[bi][0] = *(const float4*)(Yw + (size_t)(kb + (t + 3) * 32 + dT) * 256 + col0 + c8);
            by[bi][1] = *(const float4*)(Yw + (size_t)(kb + (t + 3) * 32 + dT) * 256 + col0 + c8 + 4);
        }
        if (t + 1 < NT) {
            const int bi = (t + 1) & 3;
            ushort* la = LA + ((t + 1) & 3) * 2048;
            ushort* lb = LB + ((t + 1) & 3) * 2048;
            if (XT) scatw(la, c8, dT, bx[bi][0], bx[bi][1]);
            else    cvtw16(la + wadr, bx[bi][0], bx[bi][1]);
            scatw(lb, c8, dT, by[bi][0], by[bi][1]);
        }
        asm volatile("s_waitcnt lgkmcnt(0)" ::: "memory");
        __builtin_amdgcn_s_barrier();
        __builtin_amdgcn_sched_barrier(0);
        const ushort* pa = LA + (t & 3) * 2048;
        const ushort* pb = LB + (t & 3) * 2048;
        s8v a[2], b[2];
#pragma unroll
        for (int m = 0; m < 2; ++m) {
            int row = wr * 32 + m * 16 + rA;
            a[m] = *(const s8v*)&pa[row * 32 + ((kg ^ fsw(row)) << 3)];
        }
#pragma unroll
        for (int n = 0; n < 2; ++n) {
            int row = wc * 32 + n * 16 + rA;
            b[n] = *(const s8v*)&pb[row * 32 + ((kg ^ fsw(row)) << 3)];
        }
#pragma unroll
        for (int m = 0; m < 2; ++m)
#pragma unroll
            for (int n = 0; n < 2; ++n)
                acc[m][n] = __builtin_amdgcn_mfma_f32_16x16x32_bf16(a[m], b[n], acc[m][n], 0, 0, 0);
    }
    __syncthreads();
    float* red = (float*)lds;
    if (g == 1) {
#pragma unroll
        for (int m = 0; m < 2; ++m)
#pragma unroll
            for (int n = 0; n < 2; ++n)
                *(f4v*)&red[(w4 * 64 + lane) * 16 + (m * 2 + n) * 4] = acc[m][n];
    }
    __syncthreads();
    if (g == 0) {
        int r4 = (lane >> 4) * 4, cl = lane & 15;
#pragma unroll
        for (int m = 0; m < 2; ++m)
#pragma unroll
            for (int n = 0; n < 2; ++n) {
                f4v o = *(const f4v*)&red[(w4 * 64 + lane) * 16 + (m * 2 + n) * 4];
                f4v s = acc[m][n] + o;
                int row = row0 + wr * 32 + m * 16 + r4;
                int col = col0 + wc * 32 + n * 16 + cl;
#pragma unroll
                for (int r = 0; r < 4; ++r)
                    O[(size_t)(row + r) * ldo + col] = f2bf(s[r]);
            }
    }
}

// ===== 64x64 bf16 GEMM (gload_lds), 8-wave split-K — GT stage (K=1024) =====
__device__ __forceinline__ void gemm64x8(
    const ushort* __restrict__ Xb, const ushort* __restrict__ Yb,
    int ldx, int ldy, ushort* lds, int row0, int col0, int K,
    ushort* __restrict__ O, int ldo) {
    const int tid = threadIdx.x, wave = tid >> 6, lane = tid & 63;
    const int g = wave >> 2, w4 = wave & 3;
    const int wr = w4 >> 1, wc = w4 & 1;
    const int rA = lane & 15, kg = lane >> 4;
    const int srow = w4 * 16 + (lane >> 2);
    const int scol = ((lane & 3) ^ fsw(srow)) * 8;
    const int K2 = K >> 1, NT = K2 >> 5, kb = g * K2;
    ushort* LA = lds + g * 16384;
    ushort* LB = LA + 8192;
    f4v acc[2][2] = {};
    __syncthreads();
    const ushort* gx = Xb + (size_t)(row0 + srow) * ldx + kb + scol;
    const ushort* gy = Yb + (size_t)(col0 + srow) * ldy + kb + scol;
    gload16(gx,      LA + w4 * 512);
    gload16(gy,      LB + w4 * 512);
    gload16(gx + 32, LA + 2048 + w4 * 512);
    gload16(gy + 32, LB + 2048 + w4 * 512);
    for (int t = 0; t < NT; ++t) {
        if (t + 2 < NT) {
            int s2 = (t + 2) & 3, kt = (t + 2) << 5;
            gload16(gx + kt, LA + s2 * 2048 + w4 * 512);
            gload16(gy + kt, LB + s2 * 2048 + w4 * 512);
            asm volatile("s_waitcnt vmcnt(4)" ::: "memory");
        } else if (t + 1 < NT) {
            asm volatile("s_waitcnt vmcnt(2)" ::: "memory");
        } else {
            asm volatile("s_waitcnt vmcnt(0)" ::: "memory");
        }
        __builtin_amdgcn_s_barrier();
        __builtin_amdgcn_sched_barrier(0);
        const ushort* pa = LA + (t & 3) * 2048;
        const ushort* pb = LB + (t & 3) * 2048;
        s8v a[2], b[2];
#pragma unroll
        for (int m = 0; m < 2; ++m) {
            int row = wr * 32 + m * 16 + rA;
            a[m] = *(const s8v*)&pa[row * 32 + ((kg ^ fsw(row)) << 3)];
        }
#pragma unroll
        for (int n = 0; n < 2; ++n) {
            int row = wc * 32 + n * 16 + rA;
            b[n] = *(const s8v*)&pb[row * 32 + ((kg ^ fsw(row)) << 3)];
        }
#pragma unroll
        for (int m = 0; m < 2; ++m)
#pragma unroll
            for (int n = 0; n < 2; ++n)
                acc[m][n] = __builtin_amdgcn_mfma_f32_16x16x32_bf16(a[m], b[n], acc[m][n], 0, 0, 0);
    }
    __syncthreads();
    float* red = (float*)lds;
    if (g == 1) {
#pragma unroll
        for (int m = 0; m < 2; ++m)
#pragma unroll
            for (int n = 0; n < 2; ++n)
                *(f4v*)&red[(w4 * 64 + lane) * 16 + (m * 2 + n) * 4] = acc[m][n];
    }
    __syncthreads();
    if (g == 0) {
        int r4 = (lane >> 4) * 4, cl = lane & 15;
#pragma unroll
        for (int m = 0; m < 2; ++m)
#pragma unroll
            for (int n = 0; n < 2; ++n) {
                f4v o = *(const f4v*)&red[(w4 * 64 + lane) * 16 + (m * 2 + n) * 4];
                f4v s = acc[m][n] + o;
                int row = row0 + wr * 32 + m * 16 + r4;
                int col = col0 + wc * 32 + n * 16 + cl;
#pragma unroll
                for (int r = 0; r < 4; ++r)
                    O[(size_t)(row + r) * ldo + col] = f2bf(s[r]);
            }
    }
}

// ===== 128x128 bf16 GEMM (gload_lds), 8 waves (2x4), acc 4x2 — T1 stage =====
__device__ __forceinline__ void gemm128x8(
    const ushort* __restrict__ Xb, const ushort* __restrict__ Yb,
    int ldx, int ldy, ushort* lds, int row0, int col0, int K,
    ushort* __restrict__ O, int ldo) {
    const int tid = threadIdx.x, wave = tid >> 6, lane = tid & 63;
    const int wr = wave >> 2, wc = wave & 3;
    const int rA = lane & 15, kg = lane >> 4;
    const int srow = wave * 16 + (lane >> 2);
    const int scol = ((lane & 3) ^ fsw(srow)) * 8;
    const int NT = K >> 5;
    ushort* LA = lds;
    ushort* LB = lds + 16384;
    f4v acc[4][2] = {};
    __syncthreads();
    const ushort* gx = Xb + (size_t)(row0 + srow) * ldx + scol;
    const ushort* gy = Yb + (size_t)(col0 + srow) * ldy + scol;
#pragma unroll
    for (int p = 0; p < 2; ++p) {
        gload16(gx + p * 32, LA + p * 4096 + wave * 512);
        gload16(gy + p * 32, LB + p * 4096 + wave * 512);
    }
    for (int t = 0; t < NT; ++t) {
        if (t + 2 < NT) {
            int s2 = (t + 2) & 3, kt = (t + 2) << 5;
            gload16(gx + kt, LA + s2 * 4096 + wave * 512);
            gload16(gy + kt, LB + s2 * 4096 + wave * 512);
            asm volatile("s_waitcnt vmcnt(4)" ::: "memory");
        } else if (t + 1 < NT) {
            asm volatile("s_waitcnt vmcnt(2)" ::: "memory");
        } else {
            asm volatile("s_waitcnt vmcnt(0)" ::: "memory");
        }
        __builtin_amdgcn_s_barrier();
        __builtin_amdgcn_sched_barrier(0);
        const ushort* pa = LA + (t & 3) * 4096;
        const ushort* pb = LB + (t & 3) * 4096;
        s8v a[4], b[2];
#pragma unroll
        for (int m = 0; m < 4; ++m) {
            int row = wr * 64 + m * 16 + rA;
            a[m] = *(const s8v*)&pa[row * 32 + ((kg ^ fsw(row)) << 3)];
        }
#pragma unroll
        for (int n = 0; n < 2; ++n) {
            int row = wc * 32 + n * 16 + rA;
            b[n] = *(const s8v*)&pb[row * 32 + ((kg ^ fsw(row)) << 3)];
        }
#pragma unroll
        for (int m = 0; m < 4; ++m)
#pragma unroll
            for (int n = 0; n < 2; ++n)
                acc[m][n] = __builtin_amdgcn_mfma_f32_16x16x32_bf16(a[m], b[n], acc[m][n], 0, 0, 0);
    }
    int r4 = (lane >> 4) * 4, cl = lane & 15;
#pragma unroll
    for (int m = 0; m < 4; ++m)
#pragma unroll
        for (int n = 0; n < 2; ++n) {
            int row = row0 + wr * 64 + m * 16 + r4;
            int col = col0 + wc * 32 + n * 16 + cl;
#pragma unroll
            for (int r = 0; r < 4; ++r)
                O[(size_t)(row + r) * ldo + col] = f2bf(acc[m][n][r]);
        }
}

// ===== OUT: 128x128, A = GT (bf16, gload_lds), B = x native fp32 (ld 1024),
//            transposed reg->LDS staging; fp32 out + bias. K=256.
__device__ __forceinline__ void gemmOUT(
    const ushort* __restrict__ Ga, const float* __restrict__ Xf,
    ushort* lds, int row0, int col0,
    float* __restrict__ O, const float* __restrict__ bias) {
    const int tid = threadIdx.x, wave = tid >> 6, lane = tid & 63;
    const int wr = wave >> 2, wc = wave & 3;
    const int rA = lane & 15, kg = lane >> 4;
    const int srowA = wave * 16 + (lane >> 2);
    const int scolA = ((lane & 3) ^ fsw(srowA)) * 8;
    ushort* LA = lds;              // 4 slots x 4096 ushorts
    ushort* LB = lds + 16384;
    const int kk = tid >> 4, l8 = (tid & 15) * 8;
    int wadr[8];
#pragma unroll
    for (int i = 0; i < 8; ++i) {
        int row = l8 + i;
        wadr[i] = row * 32 + (((kk >> 3) ^ fsw(row)) << 3) + (kk & 7);
    }
    const ushort* gA = Ga + (size_t)(row0 + srowA) * 256 + scolA;
    const float* gB = Xf + (size_t)kk * 1024 + col0 + l8;
    f4v acc[4][2] = {};
    __syncthreads();

    float4 ra[4], rb[4];           // rotating B-reg slots (pairs)
    gload16(gA + 0, LA + 0 * 4096 + wave * 512);
    ra[0] = *(const float4*)(gB);
    rb[0] = *(const float4*)(gB + 4);
    gload16(gA + 32, LA + 1 * 4096 + wave * 512);
    ra[1] = *(const float4*)(gB + 32768);
    rb[1] = *(const float4*)(gB + 32768 + 4);
    asm volatile("s_waitcnt vmcnt(0)" ::: "memory");
    {
        float v[8] = { ra[0].x, ra[0].y, ra[0].z, ra[0].w, rb[0].x, rb[0].y, rb[0].z, rb[0].w };
#pragma unroll
        for (int i = 0; i < 8; ++i) LB[wadr[i]] = f2bf(v[i]);
    }
    asm volatile("s_waitcnt lgkmcnt(0)" ::: "memory");
    __builtin_amdgcn_s_barrier();
    __builtin_amdgcn_sched_barrier(0);

#pragma unroll
    for (int t = 0; t < 8; ++t) {
        if (t + 1 < 8) {
            if (t + 2 < 8) {
                gload16(gA + (t + 2) * 32, LA + ((t + 2) & 3) * 4096 + wave * 512);
                ra[(t + 2) & 3] = *(const float4*)(gB + (size_t)(t + 2) * 32768);
                rb[(t + 2) & 3] = *(const float4*)(gB + (size_t)(t + 2) * 32768 + 4);
            }
            {
                const int bi = (t + 1) & 3;
                float v[8] = { ra[bi].x, ra[bi].y, ra[bi].z, ra[bi].w,
                               rb[bi].x, rb[bi].y, rb[bi].z, rb[bi].w };
                ushort* lb = LB + bi * 4096;
#pragma unroll
                for (int i = 0; i < 8; ++i) lb[wadr[i]] = f2bf(v[i]);
            }
            if (t + 2 < 8) { asm volatile("s_waitcnt vmcnt(3)" ::: "memory"); }
            else           { asm volatile("s_waitcnt vmcnt(0)" ::: "memory"); }
            asm volatile("s_waitcnt lgkmcnt(0)" ::: "memory");
            __builtin_amdgcn_s_barrier();
            __builtin_amdgcn_sched_barrier(0);
        }
        const ushort* pa = LA + (t & 3) * 4096;
        const ushort* pb = LB + (t & 3) * 4096;
        s8v a[4], b[2];
#pragma unroll
        for (int m = 0; m < 4; ++m) {
            int row = wr * 64 + m * 16 + rA;
            a[m] = *(const s8v*)&pa[row * 32 + ((kg ^ fsw(row)) << 3)];
        }
#pragma unroll
        for (int n = 0; n < 2; ++n) {
            int row = wc * 32 + n * 16 + rA;
            b[n] = *(const s8v*)&pb[row * 32 + ((kg ^ fsw(row)) << 3)];
        }
#pragma unroll
        for (int m = 0; m < 4; ++m)
#pragma unroll
            for (int n = 0; n < 2; ++n)
                acc[m][n] = __builtin_amdgcn_mfma_f32_16x16x32_bf16(a[m], b[n], acc[m][n], 0, 0, 0);
    }
    int r4 = (lane >> 4) * 4, cl = lane & 15;
#pragma unroll
    for (int m = 0; m < 4; ++m)
#pragma unroll
        for (int n = 0; n < 2; ++n) {
            int row = row0 + wr * 64 + m * 16 + r4;
            int col = col0 + wc * 32 + n * 16 + cl;
#pragma unroll
            for (int r = 0; r < 4; ++r)
                O[(size_t)(row + r) * 1024 + col] = acc[m][n][r] + bias[row + r];
        }
}

// ===== kernel 1: 224 blocks.
//   0..159  : S upper-triangular tiles (10/batch, mirror off-diagonal), XCD-mapped
//   160..223: A = Wq^T @ Wk (64 tiles) — runs CONCURRENTLY with S (no serial tail)
__global__ __launch_bounds__(512, 2) void kSP(
    const float* __restrict__ x, const float* __restrict__ Wq,
    const float* __restrict__ Wk,
    ushort* __restrict__ S16, ushort* __restrict__ A16) {
    __shared__ __align__(16) ushort lds[32768];
    const int bid = blockIdx.x;
    if (bid < 160) {
        int xcd = bid & 7, idx = bid >> 3;          // idx 0..19
        int b = 2 * xcd + (idx >= 10);
        int tri = (idx >= 10) ? idx - 10 : idx;     // 0..9
        // upper-triangular 4x4 tile enumeration:
        // 0..3 -> (0,0..3); 4..6 -> (1,1..3); 7..8 -> (2,2..3); 9 -> (3,3)
        int ti, tj;
        if (tri < 4)      { ti = 0; tj = tri; }
        else if (tri < 7) { ti = 1; tj = tri - 3; }
        else if (tri < 9) { ti = 2; tj = tri - 5; }
        else              { ti = 3; tj = 3; }
        const float* xb = x + (size_t)b * 262144;
        gemmS(xb, lds, ti * 64, tj * 64, S16 + (size_t)b * 65536, ti != tj);
    } else {
        int q = bid - 160, h = q >> 4, t2 = q & 15;
        gemmWT<1>(Wq + (size_t)h * 65536, Wk + (size_t)h * 65536, lds,
                  (t2 >> 2) * 64, (t2 & 3) * 64, A16 + (size_t)h * 65536, 256);
    }
}

// ===== kernel 2: 320 blocks. 0..255: T1_b[:, h*256:] = A_h @ S_b^T.
//                 256..319: BT = Wo_h @ Wv^T (64 tiles; consumed by kGT only).
__global__ __launch_bounds__(512, 2) void kT1(
    const ushort* __restrict__ A16, const ushort* __restrict__ S16,
    const float* __restrict__ Wo, const float* __restrict__ Wv,
    ushort* __restrict__ T1, ushort* __restrict__ BT) {
    __shared__ __align__(16) ushort lds[32768];
    int j = blockIdx.x;
    if (j < 256) {
        int xcd = j & 7, idx = j >> 3;
        int b = 2 * xcd + (idx >> 4), h = (idx >> 2) & 3, tile = idx & 3;
        gemm128x8(A16 + (size_t)h * 65536, S16 + (size_t)b * 65536, 256, 256, lds,
                  (tile >> 1) * 128, (tile & 1) * 128, 256,
                  T1 + (size_t)b * 262144 + h * 256, 1024);
    } else {
        int q = j - 256, h = q >> 4, t2 = q & 15;
        gemmWT<0>(Wo + (size_t)h * 256, Wv + (size_t)h * 65536, lds,
                  (t2 >> 2) * 64, (t2 & 3) * 64, BT + (size_t)h * 256, 1024);
    }
}

// ===== kernel 3: GT_b = BT @ T1_b^T (K=1024)
__global__ __launch_bounds__(512, 2) void kGT(
    const ushort* __restrict__ BT, const ushort* __restrict__ T1,
    ushort* __restrict__ GT) {
    __shared__ __align__(16) ushort lds[32768];
    int j = blockIdx.x, xcd = j & 7, idx = j >> 3;
    int b = 2 * xcd + (idx >> 4), tile = idx & 15;
    gemm64x8(BT, T1 + (size_t)b * 262144, 1024, 1024, lds,
             (tile >> 2) * 64, (tile & 3) * 64, 1024, GT + (size_t)b * 65536, 256);
}

// ===== kernel 4: out_b = GT_b @ x_b + bias (fp32, reads x natively)
__global__ __launch_bounds__(512, 2) void kOUT(
    const ushort* __restrict__ GT, const float* __restrict__ x,
    float* __restrict__ out, const float* __restrict__ bias) {
    __shared__ __align__(16) ushort lds[32768];
    int j = blockIdx.x, xcd = j & 7, idx = j >> 3;
    int b = 2 * xcd + (idx >> 4), tile = idx & 15;
    gemmOUT(GT + (size_t)b * 65536, x + (size_t)b * 262144, lds,
            (tile >> 3) * 128, (tile & 7) * 128, out + (size_t)b * 262144, bias);
}

extern "C" void kernel_launch(void* const* d_in, const int* in_sizes, int n_in,
                              void* d_out, int out_size, void* d_ws, size_t ws_size,
                              hipStream_t stream) {
    const float* x  = (const float*)d_in[0];
    const float* Wq = (const float*)d_in[1];
    const float* Wk = (const float*)d_in[2];
    const float* Wv = (const float*)d_in[3];
    const float* Wo = (const float*)d_in[4];
    const float* Wb = (const float*)d_in[5];

    char* ws = (char*)d_ws;
    ushort* T1  = (ushort*)(ws + 0);           // [16][256][1024] bf16, 8 MB
    ushort* S16 = (ushort*)(ws + 16777216);    // [16][256][256]  bf16, 2 MB
    ushort* GT  = (ushort*)(ws + 20971520);    // [16][256][256]  bf16, 2 MB
    ushort* A16 = (ushort*)(ws + 25165824);    // [4][256][256]   bf16, 512 KB
    ushort* BT  = (ushort*)(ws + 26214400);    // [256][1024]     bf16, 512 KB

    hipLaunchKernelGGL(kSP,  dim3(224), dim3(512), 0, stream, x, Wq, Wk, S16, A16);
    hipLaunchKernelGGL(kT1,  dim3(320), dim3(512), 0, stream, A16, S16, Wo, Wv, T1, BT);
    hipLaunchKernelGGL(kGT,  dim3(256), dim3(512), 0, stream, BT, T1, GT);
    hipLaunchKernelGGL(kOUT, dim3(256), dim3(512), 0, stream, GT, x, (float*)d_out, Wb);
}